// Round 1
// baseline (246.655 us; speedup 1.0000x reference)
//
#include <hip/hip_runtime.h>
#include <hip/hip_bf16.h>
#include <stdint.h>

#define NQ   300
#define CDIM 256
#define NH   8
#define HD   32
#define HWK  1024
#define HIDD 512

typedef __attribute__((ext_vector_type(8))) short short8;
typedef __attribute__((ext_vector_type(4))) float f32x4;

// ---- ws byte offsets (all 256-aligned), total ~14.05 MB ----
#define QB_OFF   0          // 300*256 bf16  (scale folded in)
#define KB_OFF   153600     // 1024*256 bf16
#define VT_OFF   677888     // [256 channel][1024 k] bf16 (v transposed)
#define AB_OFF   1202176    // 300*512 f32   a(q,f)
#define BX_OFF   1816576    // 1024*512 f32  bxy(k,f)
#define BS_OFF   3913728    // 8*300*1024 f32 bias
#define OB_OFF   13744128   // 300*256 f32 attn output

__device__ __forceinline__ short sw_bf16(float x){
  union { float f; uint32_t u; } c; c.f = x;
  uint32_t u = c.u;
  u += 0x7fffu + ((u >> 16) & 1u);   // RNE
  return (short)(u >> 16);
}

__device__ __forceinline__ uint32_t pk_bf16(float a, float b){
  __hip_bfloat162 h = __float22bfloat162_rn(make_float2(a, b));
  uint32_t u; __builtin_memcpy(&u, &h, 4);
  return u;
}

// ---------------- prep: a(q,f), bxy(k,f) ----------------
__global__ __launch_bounds__(256) void prep_kernel(
    const float* __restrict__ refp, const float* __restrict__ W1,
    const float* __restrict__ b1,
    float* __restrict__ ab, float* __restrict__ bx)
{
  int idx = blockIdx.x * 256 + threadIdx.x;
  const int totA = NQ * HIDD;
  if (idx < totA){
    int q = idx / HIDD, f = idx % HIDD;
    float2 w = ((const float2*)W1)[f];
    ab[idx] = w.x * refp[2*q] + w.y * refp[2*q+1] + b1[f];
  } else {
    int j = idx - totA;
    if (j < HWK * HIDD){
      int k = j / HIDD, f = j % HIDD;
      float2 w = ((const float2*)W1)[f];
      float kx = ((float)(k & 31) + 0.5f) * (1.0f/32.0f);
      float ky = ((float)(k >> 5) + 0.5f) * (1.0f/32.0f);
      bx[j] = w.x * kx + w.y * ky;
    }
  }
}

// ---------------- generic projection GEMM ----------------
// block: 16 rows x 128 cols, K-loop in chunks of 32 staged in LDS.
// mode 0: q -> QB bf16 (scaled); 1: k -> KB bf16; 2: v -> VT bf16 transposed; 3: final -> d_out f32
__global__ __launch_bounds__(256) void proj_kernel(
    const float* __restrict__ rq, const float* __restrict__ qp,
    const float* __restrict__ rs, const float* __restrict__ spe,
    const float* __restrict__ Wq, const float* __restrict__ bq,
    const float* __restrict__ Wk, const float* __restrict__ bk,
    const float* __restrict__ Wv, const float* __restrict__ bv,
    const float* __restrict__ Wo, const float* __restrict__ bo,
    char* __restrict__ ws, float* __restrict__ dout, int final_mode)
{
  int bxid = blockIdx.x;
  int tile = bxid >> 1, half = bxid & 1;
  const float *in1, *in2, *W, *bias;
  int r0, M, mode;
  if (final_mode){
    in1 = (const float*)(ws + OB_OFF); in2 = nullptr; W = Wo; bias = bo;
    r0 = tile*16; M = NQ; mode = 3;
  } else if (tile < 19){
    in1 = rq; in2 = qp; W = Wq; bias = bq; r0 = tile*16; M = NQ; mode = 0;
  } else if (tile < 83){
    in1 = rs; in2 = spe; W = Wk; bias = bk; r0 = (tile-19)*16; M = HWK; mode = 1;
  } else {
    in1 = rs; in2 = spe; W = Wv; bias = bv; r0 = (tile-83)*16; M = HWK; mode = 2;
  }
  __shared__ __align__(16) float At[32][20];   // [c][row], padded, f4-aligned rows
  __shared__ float Wl[32][129];                // [c][n], pad 129 -> conflict-free
  int tid = threadIdx.x;
  int n_loc = tid & 127;
  int rg = tid >> 7;                  // rows rg*8 .. rg*8+7
  int n = half*128 + n_loc;
  float acc[8];
  float bv_ = bias[n];
  #pragma unroll
  for (int i=0;i<8;i++) acc[i] = bv_;

  for (int c0 = 0; c0 < CDIM; c0 += 32){
    __syncthreads();
    for (int e = tid; e < 512; e += 256){
      int r = e >> 5, c = e & 31;
      int gr = r0 + r; if (gr >= M) gr = M - 1;
      float v = in1[gr*CDIM + c0 + c];
      if (in2) v += in2[gr*CDIM + c0 + c];
      At[c][r] = v;
    }
    for (int e = tid; e < 4096; e += 256){
      int c = e & 31, nn = e >> 5;
      Wl[c][nn] = W[(half*128 + nn)*CDIM + c0 + c];
    }
    __syncthreads();
    #pragma unroll
    for (int c = 0; c < 32; c++){
      float w = Wl[c][n_loc];
      const float4* ap = (const float4*)&At[c][rg*8];
      float4 a0 = ap[0], a1 = ap[1];
      acc[0] = fmaf(a0.x, w, acc[0]);
      acc[1] = fmaf(a0.y, w, acc[1]);
      acc[2] = fmaf(a0.z, w, acc[2]);
      acc[3] = fmaf(a0.w, w, acc[3]);
      acc[4] = fmaf(a1.x, w, acc[4]);
      acc[5] = fmaf(a1.y, w, acc[5]);
      acc[6] = fmaf(a1.z, w, acc[6]);
      acc[7] = fmaf(a1.w, w, acc[7]);
    }
  }

  if (mode == 0){
    short* qb = (short*)(ws + QB_OFF);
    const float s = 0.17677669529663687f;  // 1/sqrt(32), folded into q
    #pragma unroll
    for (int i=0;i<8;i++){
      int gr = r0 + rg*8 + i;
      if (gr < M) qb[gr*CDIM + n] = sw_bf16(acc[i]*s);
    }
  } else if (mode == 1){
    short* kb = (short*)(ws + KB_OFF);
    #pragma unroll
    for (int i=0;i<8;i++){
      int gr = r0 + rg*8 + i;
      if (gr < M) kb[gr*CDIM + n] = sw_bf16(acc[i]);
    }
  } else if (mode == 2){
    short* vt = (short*)(ws + VT_OFF);
    union { short8 s; uint32_t u[4]; } p;
    #pragma unroll
    for (int i=0;i<4;i++) p.u[i] = pk_bf16(acc[2*i], acc[2*i+1]);
    *(short8*)(vt + n*HWK + r0 + rg*8) = p.s;   // 8 consecutive k per thread
  } else {
    #pragma unroll
    for (int i=0;i<8;i++){
      int gr = r0 + rg*8 + i;
      if (gr < M) dout[gr*CDIM + n] = acc[i];
    }
  }
}

// ---------------- bias: relu(a-bxy) @ W2^T via MFMA ----------------
// grid 600 = 75 q-groups(4) x 8 k-groups(128). wave: 2 ktiles of 16 k.
// MFMA: A[m=k-pair][kk=f] = relu, B[kk=f][n=head] = W2. D row=k, col=head.
__global__ __launch_bounds__(256) void bias_kernel(
    const float* __restrict__ ab, const float* __restrict__ bx,
    const float* __restrict__ W2, float* __restrict__ bs)
{
  int bid = blockIdx.x;
  int qg = bid >> 3, kg = bid & 7;
  int q0 = qg * 4;
  int k0b = kg * 128;
  int tid = threadIdx.x, wave = tid >> 6, lane = tid & 63;
  int n = lane & 15, qd = lane >> 4;

  short8 w2f[16];
  #pragma unroll
  for (int kc = 0; kc < 16; kc++){
    if (n < 8){
      const float4* p = (const float4*)(W2 + n*HIDD + kc*32 + qd*8);
      float4 x0 = p[0], x1 = p[1];
      union { short8 s; uint32_t u[4]; } t;
      t.u[0] = pk_bf16(x0.x, x0.y);
      t.u[1] = pk_bf16(x0.z, x0.w);
      t.u[2] = pk_bf16(x1.x, x1.y);
      t.u[3] = pk_bf16(x1.z, x1.w);
      w2f[kc] = t.s;
    } else {
      short8 z = {0,0,0,0,0,0,0,0};
      w2f[kc] = z;
    }
  }

  for (int t = 0; t < 2; t++){
    int k0 = k0b + (wave*2 + t)*16;
    int krow = k0 + n;
    f32x4 acc[4];
    #pragma unroll
    for (int q=0;q<4;q++){ f32x4 z = {0.f,0.f,0.f,0.f}; acc[q] = z; }
    const float* brow = bx + krow*HIDD;
    const float* arow = ab + q0*HIDD;
    #pragma unroll 4
    for (int kc = 0; kc < 16; kc++){
      int f0 = kc*32 + qd*8;
      const float4* bp = (const float4*)(brow + f0);
      float4 b0 = bp[0], b1 = bp[1];
      #pragma unroll
      for (int q = 0; q < 4; q++){
        const float4* apf = (const float4*)(arow + q*HIDD + f0);
        float4 a0 = apf[0], a1 = apf[1];
        union { short8 s; uint32_t u[4]; } r;
        r.u[0] = pk_bf16(fmaxf(a0.x-b0.x,0.f), fmaxf(a0.y-b0.y,0.f));
        r.u[1] = pk_bf16(fmaxf(a0.z-b0.z,0.f), fmaxf(a0.w-b0.w,0.f));
        r.u[2] = pk_bf16(fmaxf(a1.x-b1.x,0.f), fmaxf(a1.y-b1.y,0.f));
        r.u[3] = pk_bf16(fmaxf(a1.z-b1.z,0.f), fmaxf(a1.w-b1.w,0.f));
        acc[q] = __builtin_amdgcn_mfma_f32_16x16x32_bf16(r.s, w2f[kc], acc[q], 0, 0, 0);
      }
    }
    if (n < 8){
      #pragma unroll
      for (int q = 0; q < 4; q++){
        float* dst = bs + ((size_t)(n*NQ + q0 + q))*HWK + k0 + qd*4;
        *(f32x4*)dst = acc[q];   // D rows quad*4+reg are k-consecutive -> f32x4
      }
    }
  }
}

// ---------------- attn: logits MFMA + softmax + PV MFMA ----------------
// grid 600 = 8 heads x 75 q-groups(4). scores kept f32 in LDS for softmax; p in bf16.
__global__ __launch_bounds__(256) void attn_kernel(
    const short* __restrict__ qb, const short* __restrict__ kb,
    const short* __restrict__ vt, const float* __restrict__ bs,
    float* __restrict__ ob)
{
  int bid = blockIdx.x;
  int h = bid & 7, qg = bid >> 3;
  int q0 = qg * 4;
  int tid = threadIdx.x, wave = tid >> 6, lane = tid & 63;
  int n = lane & 15, qd = lane >> 4;

  __shared__ __align__(16) float sc32[4][1028];   // f32 scores for softmax
  __shared__ __align__(16) short pb[16][1032];    // bf16 p for PV MFMA (rows 4..15 zero)
  __shared__ float rsum[4];
  __shared__ __align__(16) f32x4 part[8][64];     // [wave*2+ntile][lane]

  for (int e = tid; e < 12*1032; e += 256) (&pb[4][0])[e] = 0;

  // A-frag: q rows (m = lane&15, valid m<4)
  short8 afrag;
  if (n < 4){
    afrag = *(const short8*)(qb + (q0+n)*CDIM + h*HD + qd*8);
  } else {
    short8 z = {0,0,0,0,0,0,0,0}; afrag = z;
  }

  // phase 1: logits + bias -> sc32
  #pragma unroll 4
  for (int i = 0; i < 16; i++){
    int k0 = (wave*16 + i) * 16;
    short8 bfrag = *(const short8*)(kb + (k0+n)*CDIM + h*HD + qd*8);
    f32x4 d = {0.f,0.f,0.f,0.f};
    d = __builtin_amdgcn_mfma_f32_16x16x32_bf16(afrag, bfrag, d, 0, 0, 0);
    if (qd == 0){
      #pragma unroll
      for (int r = 0; r < 4; r++){
        sc32[r][k0 + n] = d[r] + bs[((size_t)(h*NQ + q0 + r))*HWK + k0 + n];
      }
    }
  }
  __syncthreads();

  // phase 2: softmax, row = wave (0..3)
  {
    int row = wave;
    float vals[16];
    float mx = -3.0e38f;
    #pragma unroll
    for (int j = 0; j < 16; j++){
      float v = sc32[row][lane + 64*j];
      vals[j] = v;
      mx = fmaxf(mx, v);
    }
    #pragma unroll
    for (int off = 32; off >= 1; off >>= 1) mx = fmaxf(mx, __shfl_xor(mx, off));
    float sum = 0.f;
    #pragma unroll
    for (int j = 0; j < 16; j++){ float p = __expf(vals[j] - mx); vals[j] = p; sum += p; }
    #pragma unroll
    for (int off = 32; off >= 1; off >>= 1) sum += __shfl_xor(sum, off);
    if (lane == 0) rsum[row] = 1.0f / sum;
    // write p bf16: element k = lane + 64*j -> pack pairs at 2*lane + 128*jj
    #pragma unroll
    for (int j = 0; j < 8; j++){
      float plo = vals[2*j] , phi = vals[2*j+1];
      // careful: vals[j] corresponds to k = lane + 64*j (strided). Repack via LDS-consistent scheme:
      (void)plo; (void)phi;
    }
    // simple correct path: scalar bf16 stores at the strided positions
    #pragma unroll
    for (int j = 0; j < 16; j++){
      pb[row][lane + 64*j] = sw_bf16(vals[j]);
    }
  }
  __syncthreads();

  // phase 3: PV. wave handles kc = wave*8 .. wave*8+7 (k = 256 per wave)
  f32x4 o0 = {0.f,0.f,0.f,0.f}, o1 = {0.f,0.f,0.f,0.f};
  #pragma unroll
  for (int i = 0; i < 8; i++){
    int kbase = (wave*8 + i)*32 + qd*8;
    short8 pa = *(const short8*)&pb[n][kbase];
    short8 v0 = *(const short8*)(vt + ((size_t)(h*HD + n))*HWK + kbase);
    short8 v1 = *(const short8*)(vt + ((size_t)(h*HD + 16 + n))*HWK + kbase);
    o0 = __builtin_amdgcn_mfma_f32_16x16x32_bf16(pa, v0, o0, 0, 0, 0);
    o1 = __builtin_amdgcn_mfma_f32_16x16x32_bf16(pa, v1, o1, 0, 0, 0);
  }
  part[wave*2+0][lane] = o0;
  part[wave*2+1][lane] = o1;
  __syncthreads();

  // reduce partials across waves and write
  {
    int L = tid & 63;
    int sel = tid >> 6;
    int nt = sel >> 1, rp = sel & 1;
    int nn = L & 15, qdd = L >> 4;
    #pragma unroll
    for (int rr = 0; rr < 2; rr++){
      int reg = rp*2 + rr;
      int q = qdd*4 + reg;
      if (q < 4){
        float s = part[0+nt][L][reg] + part[2+nt][L][reg]
                + part[4+nt][L][reg] + part[6+nt][L][reg];
        ob[(q0+q)*CDIM + h*HD + nt*16 + nn] = s * rsum[q];
      }
    }
  }
}

extern "C" void kernel_launch(void* const* d_in, const int* in_sizes, int n_in,
                              void* d_out, int out_size, void* d_ws, size_t ws_size,
                              hipStream_t stream)
{
  const float* rq  = (const float*)d_in[0];
  const float* qp  = (const float*)d_in[1];
  const float* rp  = (const float*)d_in[2];
  const float* rs  = (const float*)d_in[3];
  const float* spe = (const float*)d_in[4];
  const float* Wq  = (const float*)d_in[5];
  const float* bq  = (const float*)d_in[6];
  const float* Wk  = (const float*)d_in[7];
  const float* bk  = (const float*)d_in[8];
  const float* Wv  = (const float*)d_in[9];
  const float* bv  = (const float*)d_in[10];
  const float* Wo  = (const float*)d_in[11];
  const float* bo  = (const float*)d_in[12];
  const float* W1  = (const float*)d_in[13];
  const float* b1  = (const float*)d_in[14];
  const float* W2  = (const float*)d_in[15];
  char* ws = (char*)d_ws;
  float* dout = (float*)d_out;

  prep_kernel<<<2648, 256, 0, stream>>>(rp, W1, b1,
      (float*)(ws + AB_OFF), (float*)(ws + BX_OFF));
  proj_kernel<<<294, 256, 0, stream>>>(rq, qp, rs, spe, Wq, bq, Wk, bk,
      Wv, bv, Wo, bo, ws, dout, 0);
  bias_kernel<<<600, 256, 0, stream>>>((const float*)(ws + AB_OFF),
      (const float*)(ws + BX_OFF), W2, (float*)(ws + BS_OFF));
  attn_kernel<<<600, 256, 0, stream>>>((const short*)(ws + QB_OFF),
      (const short*)(ws + KB_OFF), (const short*)(ws + VT_OFF),
      (const float*)(ws + BS_OFF), (float*)(ws + OB_OFF));
  proj_kernel<<<38, 256, 0, stream>>>(rq, qp, rs, spe, Wq, bq, Wk, bk,
      Wv, bv, Wo, bo, ws, dout, 1);
}

// Round 2
// 206.175 us; speedup vs baseline: 1.1963x; 1.1963x over previous
//
#include <hip/hip_runtime.h>
#include <hip/hip_bf16.h>
#include <stdint.h>

#define NQ   300
#define CDIM 256
#define NH   8
#define HD   32
#define HWK  1024
#define HIDD 512

typedef __attribute__((ext_vector_type(8))) short short8;
typedef __attribute__((ext_vector_type(4))) float f32x4;

// ---- ws byte offsets (all 256-aligned), total ~14.05 MB ----
#define QB_OFF   0          // 300*256 bf16  (scale folded in), [q][c]
#define KB_OFF   153600     // 8*1024*32 bf16, [h][k][d]
#define VT_OFF   677888     // [256 channel][1024 k] bf16 (v transposed)
#define AB_OFF   1202176    // 300*512 f32   a(q,f)
#define BX_OFF   1816576    // 1024*512 f32  bxy(k,f)
#define BS_OFF   3913728    // 300*8*1024 f32 bias, [q][h][k]
#define OB_OFF   13744128   // 300*256 f32 attn output

__device__ __forceinline__ short sw_bf16(float x){
  union { float f; uint32_t u; } c; c.f = x;
  uint32_t u = c.u;
  u += 0x7fffu + ((u >> 16) & 1u);   // RNE
  return (short)(u >> 16);
}

__device__ __forceinline__ uint32_t pk_bf16(float a, float b){
  __hip_bfloat162 h = __float22bfloat162_rn(make_float2(a, b));
  uint32_t u; __builtin_memcpy(&u, &h, 4);
  return u;
}

// ---------------- prep: a(q,f), bxy(k,f) ----------------
__global__ __launch_bounds__(256) void prep_kernel(
    const float* __restrict__ refp, const float* __restrict__ W1,
    const float* __restrict__ b1,
    float* __restrict__ ab, float* __restrict__ bx)
{
  int idx = blockIdx.x * 256 + threadIdx.x;
  const int totA = NQ * HIDD;
  if (idx < totA){
    int q = idx / HIDD, f = idx % HIDD;
    float2 w = ((const float2*)W1)[f];
    ab[idx] = w.x * refp[2*q] + w.y * refp[2*q+1] + b1[f];
  } else {
    int j = idx - totA;
    if (j < HWK * HIDD){
      int k = j / HIDD, f = j % HIDD;
      float2 w = ((const float2*)W1)[f];
      float kx = ((float)(k & 31) + 0.5f) * (1.0f/32.0f);
      float ky = ((float)(k >> 5) + 0.5f) * (1.0f/32.0f);
      bx[j] = w.x * kx + w.y * ky;
    }
  }
}

// ---------------- generic projection GEMM ----------------
// mode 0: q -> QB bf16 (scaled); 1: k -> KB bf16 [h][k][d]; 2: v -> VT bf16 transposed; 3: final -> d_out f32
__global__ __launch_bounds__(256) void proj_kernel(
    const float* __restrict__ rq, const float* __restrict__ qp,
    const float* __restrict__ rs, const float* __restrict__ spe,
    const float* __restrict__ Wq, const float* __restrict__ bq,
    const float* __restrict__ Wk, const float* __restrict__ bk,
    const float* __restrict__ Wv, const float* __restrict__ bv,
    const float* __restrict__ Wo, const float* __restrict__ bo,
    char* __restrict__ ws, float* __restrict__ dout, int final_mode)
{
  int bxid = blockIdx.x;
  int tile = bxid >> 1, half = bxid & 1;
  const float *in1, *in2, *W, *bias;
  int r0, M, mode;
  if (final_mode){
    in1 = (const float*)(ws + OB_OFF); in2 = nullptr; W = Wo; bias = bo;
    r0 = tile*16; M = NQ; mode = 3;
  } else if (tile < 19){
    in1 = rq; in2 = qp; W = Wq; bias = bq; r0 = tile*16; M = NQ; mode = 0;
  } else if (tile < 83){
    in1 = rs; in2 = spe; W = Wk; bias = bk; r0 = (tile-19)*16; M = HWK; mode = 1;
  } else {
    in1 = rs; in2 = spe; W = Wv; bias = bv; r0 = (tile-83)*16; M = HWK; mode = 2;
  }
  __shared__ __align__(16) float At[32][20];
  __shared__ float Wl[32][129];
  int tid = threadIdx.x;
  int n_loc = tid & 127;
  int rg = tid >> 7;                  // rows rg*8 .. rg*8+7
  int n = half*128 + n_loc;
  float acc[8];
  float bv_ = bias[n];
  #pragma unroll
  for (int i=0;i<8;i++) acc[i] = bv_;

  for (int c0 = 0; c0 < CDIM; c0 += 32){
    __syncthreads();
    for (int e = tid; e < 512; e += 256){
      int r = e >> 5, c = e & 31;
      int gr = r0 + r; if (gr >= M) gr = M - 1;
      float v = in1[gr*CDIM + c0 + c];
      if (in2) v += in2[gr*CDIM + c0 + c];
      At[c][r] = v;
    }
    for (int e = tid; e < 4096; e += 256){
      int c = e & 31, nn = e >> 5;
      Wl[c][nn] = W[(half*128 + nn)*CDIM + c0 + c];
    }
    __syncthreads();
    #pragma unroll
    for (int c = 0; c < 32; c++){
      float w = Wl[c][n_loc];
      const float4* ap = (const float4*)&At[c][rg*8];
      float4 a0 = ap[0], a1 = ap[1];
      acc[0] = fmaf(a0.x, w, acc[0]);
      acc[1] = fmaf(a0.y, w, acc[1]);
      acc[2] = fmaf(a0.z, w, acc[2]);
      acc[3] = fmaf(a0.w, w, acc[3]);
      acc[4] = fmaf(a1.x, w, acc[4]);
      acc[5] = fmaf(a1.y, w, acc[5]);
      acc[6] = fmaf(a1.z, w, acc[6]);
      acc[7] = fmaf(a1.w, w, acc[7]);
    }
  }

  if (mode == 0){
    short* qb = (short*)(ws + QB_OFF);
    const float s = 0.17677669529663687f;  // 1/sqrt(32)
    #pragma unroll
    for (int i=0;i<8;i++){
      int gr = r0 + rg*8 + i;
      if (gr < M) qb[gr*CDIM + n] = sw_bf16(acc[i]*s);
    }
  } else if (mode == 1){
    short* kb = (short*)(ws + KB_OFF);
    int h = n >> 5, d = n & 31;
    #pragma unroll
    for (int i=0;i<8;i++){
      int gr = r0 + rg*8 + i;
      if (gr < M) kb[((size_t)h*HWK + gr)*HD + d] = sw_bf16(acc[i]);
    }
  } else if (mode == 2){
    short* vt = (short*)(ws + VT_OFF);
    union { short8 s; uint32_t u[4]; } p;
    #pragma unroll
    for (int i=0;i<4;i++) p.u[i] = pk_bf16(acc[2*i], acc[2*i+1]);
    *(short8*)(vt + n*HWK + r0 + rg*8) = p.s;
  } else {
    #pragma unroll
    for (int i=0;i<8;i++){
      int gr = r0 + rg*8 + i;
      if (gr < M) dout[gr*CDIM + n] = acc[i];
    }
  }
}

// ---------------- bias: relu(a-bxy) @ W2^T via MFMA ----------------
// grid 1200 = 75 qg(4) x 16 kg(64). wave -> 16 k rows. a staged in LDS;
// bias tile staged through LDS -> fully coalesced [q][h][k] store.
__global__ __launch_bounds__(256) void bias_kernel(
    const float* __restrict__ ab, const float* __restrict__ bx,
    const float* __restrict__ W2, float* __restrict__ bs)
{
  int bid = blockIdx.x;
  int qg = bid >> 4, kg = bid & 15;
  int q0 = qg * 4;
  int tid = threadIdx.x, wave = tid >> 6, lane = tid & 63;
  int n = lane & 15, qd = lane >> 4;
  int k0 = kg * 64 + wave * 16;

  __shared__ __align__(16) float al[4][HIDD];     // a rows, 8KB
  __shared__ __align__(16) float bl[4][8][68];    // bias tile staging

  for (int e = tid; e < 512; e += 256)
    ((f32x4*)al)[e] = ((const f32x4*)(ab + (size_t)q0*HIDD))[e];

  short8 w2f[16];
  #pragma unroll
  for (int kc = 0; kc < 16; kc++){
    if (n < 8){
      const float4* p = (const float4*)(W2 + n*HIDD + kc*32 + qd*8);
      float4 x0 = p[0], x1 = p[1];
      union { short8 s; uint32_t u[4]; } t;
      t.u[0] = pk_bf16(x0.x, x0.y);
      t.u[1] = pk_bf16(x0.z, x0.w);
      t.u[2] = pk_bf16(x1.x, x1.y);
      t.u[3] = pk_bf16(x1.z, x1.w);
      w2f[kc] = t.s;
    } else {
      short8 z = {0,0,0,0,0,0,0,0};
      w2f[kc] = z;
    }
  }
  __syncthreads();

  f32x4 acc[4];
  #pragma unroll
  for (int q=0;q<4;q++){ f32x4 z = {0.f,0.f,0.f,0.f}; acc[q] = z; }

  const float* brow = bx + (size_t)(k0 + n) * HIDD;
  #pragma unroll 4
  for (int kc = 0; kc < 16; kc++){
    int f0 = kc*32 + qd*8;
    float4 b0 = *(const float4*)(brow + f0);
    float4 b1 = *(const float4*)(brow + f0 + 4);
    #pragma unroll
    for (int q = 0; q < 4; q++){
      const float4* ap = (const float4*)&al[q][f0];
      float4 a0 = ap[0], a1 = ap[1];
      union { short8 s; uint32_t u[4]; } r;
      r.u[0] = pk_bf16(fmaxf(a0.x-b0.x,0.f), fmaxf(a0.y-b0.y,0.f));
      r.u[1] = pk_bf16(fmaxf(a0.z-b0.z,0.f), fmaxf(a0.w-b0.w,0.f));
      r.u[2] = pk_bf16(fmaxf(a1.x-b1.x,0.f), fmaxf(a1.y-b1.y,0.f));
      r.u[3] = pk_bf16(fmaxf(a1.z-b1.z,0.f), fmaxf(a1.w-b1.w,0.f));
      acc[q] = __builtin_amdgcn_mfma_f32_16x16x32_bf16(r.s, w2f[kc], acc[q], 0, 0, 0);
    }
  }

  // D: col = lane&15 = head (n<8), row = qd*4+reg = k-local -> f32x4 over k
  if (n < 8){
    #pragma unroll
    for (int q = 0; q < 4; q++)
      *(f32x4*)&bl[q][n][wave*16 + qd*4] = acc[q];
  }
  __syncthreads();

  // coalesced store of the whole 4q x 8h x 64k tile
  #pragma unroll
  for (int cid = tid; cid < 512; cid += 256){
    int q = cid >> 7, hh = (cid >> 4) & 7, c = cid & 15;
    f32x4 v = *(const f32x4*)&bl[q][hh][c*4];
    *(f32x4*)(bs + ((size_t)((q0+q)*NH + hh))*HWK + kg*64 + c*4) = v;
  }
}

// ---------------- attn: logits MFMA + softmax + PV MFMA ----------------
// grid 600 = 8 heads x 75 q-groups(4).
// phase1: A = K-side (m=16 k), B = Q-side -> D gives f32x4 of consecutive k per lane.
__global__ __launch_bounds__(256) void attn_kernel(
    const short* __restrict__ qb, const short* __restrict__ kb,
    const short* __restrict__ vt, const float* __restrict__ bs,
    float* __restrict__ ob)
{
  int bid = blockIdx.x;
  int h = bid & 7, qg = bid >> 3;
  int q0 = qg * 4;
  int tid = threadIdx.x, wave = tid >> 6, lane = tid & 63;
  int n = lane & 15, qd = lane >> 4;

  __shared__ __align__(16) float sc[4][1040];   // f32 scores, padded
  __shared__ __align__(16) short pb[4][1056];   // bf16 p, padded
  __shared__ float rsum[4];
  __shared__ __align__(16) f32x4 part[8][64];

  // B-frag (q side): B[kk=qd*8+j][n] = Q[q0+(n&3)][d]; cols 4..15 ignored
  short8 qfrag = *(const short8*)(qb + (q0 + (n & 3))*CDIM + h*HD + qd*8);
  const short* kbh = kb + (size_t)h * HWK * HD;

  // phase 1: logits + bias -> sc (wave covers k quarter: 16 tiles of 16)
  #pragma unroll 4
  for (int i = 0; i < 16; i++){
    int k0 = (wave*16 + i) * 16;
    short8 af = *(const short8*)(kbh + (k0 + n)*HD + qd*8);  // contiguous 1KB/wave
    f32x4 d = {0.f,0.f,0.f,0.f};
    d = __builtin_amdgcn_mfma_f32_16x16x32_bf16(af, qfrag, d, 0, 0, 0);
    if (n < 4){
      f32x4 bias = *(const f32x4*)(bs + ((size_t)((q0+n)*NH + h))*HWK + k0 + qd*4);
      d += bias;
      *(f32x4*)&sc[n][k0 + qd*4] = d;   // row=k-local -> consecutive k
    }
  }
  __syncthreads();

  // phase 2: softmax; wave w handles q-row w
  {
    float vals[16];
    float mx = -3.0e38f;
    #pragma unroll
    for (int i = 0; i < 4; i++){
      f32x4 v = *(const f32x4*)&sc[wave][i*256 + lane*4];
      #pragma unroll
      for (int j = 0; j < 4; j++){ vals[i*4+j] = v[j]; mx = fmaxf(mx, v[j]); }
    }
    #pragma unroll
    for (int off = 32; off >= 1; off >>= 1) mx = fmaxf(mx, __shfl_xor(mx, off));
    float sum = 0.f;
    #pragma unroll
    for (int j = 0; j < 16; j++){ float p = __expf(vals[j] - mx); vals[j] = p; sum += p; }
    #pragma unroll
    for (int off = 32; off >= 1; off >>= 1) sum += __shfl_xor(sum, off);
    if (lane == 0) rsum[wave] = 1.0f / sum;
    #pragma unroll
    for (int i = 0; i < 4; i++){
      uint32_t u0 = pk_bf16(vals[i*4+0], vals[i*4+1]);
      uint32_t u1 = pk_bf16(vals[i*4+2], vals[i*4+3]);
      uint2 pk = make_uint2(u0, u1);
      *(uint2*)&pb[wave][i*256 + lane*4] = pk;
    }
  }
  __syncthreads();

  // phase 3: PV; wave covers its k quarter (256 k)
  f32x4 o0 = {0.f,0.f,0.f,0.f}, o1 = {0.f,0.f,0.f,0.f};
  #pragma unroll
  for (int i = 0; i < 8; i++){
    int kb2 = wave*256 + i*32 + qd*8;
    short8 pa = *(const short8*)&pb[n & 3][kb2];
    short8 v0 = *(const short8*)(vt + ((size_t)(h*HD + n))*HWK + kb2);
    short8 v1 = *(const short8*)(vt + ((size_t)(h*HD + 16 + n))*HWK + kb2);
    o0 = __builtin_amdgcn_mfma_f32_16x16x32_bf16(pa, v0, o0, 0, 0, 0);
    o1 = __builtin_amdgcn_mfma_f32_16x16x32_bf16(pa, v1, o1, 0, 0, 0);
  }
  part[wave*2+0][lane] = o0;
  part[wave*2+1][lane] = o1;
  __syncthreads();

  // reduce partials across waves and write
  {
    int L = tid & 63;
    int sel = tid >> 6;
    int nt = sel >> 1, rp = sel & 1;
    int nn = L & 15, qdd = L >> 4;
    #pragma unroll
    for (int rr = 0; rr < 2; rr++){
      int reg = rp*2 + rr;
      int q = qdd*4 + reg;
      if (q < 4){
        float s = part[0+nt][L][reg] + part[2+nt][L][reg]
                + part[4+nt][L][reg] + part[6+nt][L][reg];
        ob[(q0+q)*CDIM + h*HD + nt*16 + nn] = s * rsum[q];
      }
    }
  }
}

extern "C" void kernel_launch(void* const* d_in, const int* in_sizes, int n_in,
                              void* d_out, int out_size, void* d_ws, size_t ws_size,
                              hipStream_t stream)
{
  const float* rq  = (const float*)d_in[0];
  const float* qp  = (const float*)d_in[1];
  const float* rp  = (const float*)d_in[2];
  const float* rs  = (const float*)d_in[3];
  const float* spe = (const float*)d_in[4];
  const float* Wq  = (const float*)d_in[5];
  const float* bq  = (const float*)d_in[6];
  const float* Wk  = (const float*)d_in[7];
  const float* bk  = (const float*)d_in[8];
  const float* Wv  = (const float*)d_in[9];
  const float* bv  = (const float*)d_in[10];
  const float* Wo  = (const float*)d_in[11];
  const float* bo  = (const float*)d_in[12];
  const float* W1  = (const float*)d_in[13];
  const float* b1  = (const float*)d_in[14];
  const float* W2  = (const float*)d_in[15];
  char* ws = (char*)d_ws;
  float* dout = (float*)d_out;

  prep_kernel<<<2648, 256, 0, stream>>>(rp, W1, b1,
      (float*)(ws + AB_OFF), (float*)(ws + BX_OFF));
  proj_kernel<<<294, 256, 0, stream>>>(rq, qp, rs, spe, Wq, bq, Wk, bk,
      Wv, bv, Wo, bo, ws, dout, 0);
  bias_kernel<<<1200, 256, 0, stream>>>((const float*)(ws + AB_OFF),
      (const float*)(ws + BX_OFF), W2, (float*)(ws + BS_OFF));
  attn_kernel<<<600, 256, 0, stream>>>((const short*)(ws + QB_OFF),
      (const short*)(ws + KB_OFF), (const short*)(ws + VT_OFF),
      (const float*)(ws + BS_OFF), (float*)(ws + OB_OFF));
  proj_kernel<<<38, 256, 0, stream>>>(rq, qp, rs, spe, Wq, bq, Wk, bk,
      Wv, bv, Wo, bo, ws, dout, 1);
}